// Round 6
// baseline (77.920 us; speedup 1.0000x reference)
//
#include <hip/hip_runtime.h>
#include <hip/hip_cooperative_groups.h>
#include <math.h>

namespace cg = cooperative_groups;

#define DIM     128
#define V_ROWS  20000
#define NPAIRS  65536
#define NFLOAT4 (V_ROWS * DIM / 4)   // 640000

constexpr int BLOCKS  = 256;
constexpr int THREADS = 256;
constexpr int NTHREADS = BLOCKS * THREADS;           // 65536
// 640000 = 9*65536 + 50176
constexpr int TAIL = NFLOAT4 - 9 * NTHREADS;         // 50176

// ws layout (floats): partial[256*128], blockpart[256]

__global__ __launch_bounds__(THREADS) void fused(
        const float4* __restrict__ emb4,
        const int* __restrict__ iv,
        const int* __restrict__ jv,
        float* __restrict__ partial,
        float* __restrict__ blockpart,
        float* __restrict__ out) {
    const cg::grid_group grid = cg::this_grid();
    const int lane = threadIdx.x & 63;
    const int wid  = threadIdx.x >> 6;

    __shared__ float sm[4][DIM];
    __shared__ float S_lds[DIM];
    __shared__ float ls[4];

    // ---------------- Phase A: per-block column partial sums ----------------
    {
        const int tid = blockIdx.x * THREADS + threadIdx.x;
        float4 a = make_float4(0.f, 0.f, 0.f, 0.f);
        #pragma unroll
        for (int k = 0; k < 9; ++k) {
            const float4 v = emb4[tid + k * NTHREADS];
            a.x += v.x; a.y += v.y; a.z += v.z; a.w += v.w;
        }
        if (tid < TAIL) {
            const float4 v = emb4[tid + 9 * NTHREADS];
            a.x += v.x; a.y += v.y; a.z += v.z; a.w += v.w;
        }
        // stride*4 % 128 == 0 -> thread's 4 cols fixed: (tid*4)&127.
        // lane l and l^32 share columns -> fold to 32 lanes.
        a.x += __shfl_xor(a.x, 32);
        a.y += __shfl_xor(a.y, 32);
        a.z += __shfl_xor(a.z, 32);
        a.w += __shfl_xor(a.w, 32);

        const int col = (threadIdx.x * 4) & 127;
        if (lane < 32) {
            sm[wid][col + 0] = a.x;
            sm[wid][col + 1] = a.y;
            sm[wid][col + 2] = a.z;
            sm[wid][col + 3] = a.w;
        }
        __syncthreads();
        if (threadIdx.x < DIM) {
            partial[blockIdx.x * DIM + threadIdx.x] =
                sm[0][threadIdx.x] + sm[1][threadIdx.x] +
                sm[2][threadIdx.x] + sm[3][threadIdx.x];
        }
    }

    grid.sync();

    // ------- Phase B: every block folds all partials -> S (own LDS) --------
    {
        const int col = threadIdx.x & 127;
        const int g   = threadIdx.x >> 7;        // 0..1
        float s = 0.f;
        #pragma unroll 8
        for (int k = 0; k < BLOCKS / 2; ++k) {   // 128 independent loads
            s += partial[(g + 2 * k) * DIM + col];
        }
        __syncthreads();                          // sm reuse barrier
        sm[g][col] = s;
        __syncthreads();
        if (threadIdx.x < DIM) S_lds[threadIdx.x] = sm[0][threadIdx.x] + sm[1][threadIdx.x];
        __syncthreads();
    }

    // ---------------- Phase C: pairs (16 lanes/pair, 64 pairs/wave) --------
    {
        const int c   = lane & 15;               // 8 cols per lane
        const int grp = lane >> 4;               // 4 pairs in flight
        const int gw  = blockIdx.x * 4 + wid;    // 0..1023
        const int base = gw * 64;

        const float4* S4 = reinterpret_cast<const float4*>(S_lds);
        const float4 s0 = S4[c * 2], s1 = S4[c * 2 + 1];

        const int i64 = iv[base + lane];         // 64 pair indices, coalesced
        const int j64 = jv[base + lane];

        float acc = 0.f;
        for (int ot = 0; ot < 4; ++ot) {
            // issue 16 row-pair gathers (4 batches x 4 pairs) before reducing
            float4 A0[4], A1[4], B0[4], B1[4];
            #pragma unroll
            for (int it = 0; it < 4; ++it) {
                const int q = ot * 16 + it * 4 + grp;
                const int i = __shfl(i64, q);
                const int j = __shfl(j64, q);
                const float4* ei = emb4 + (size_t)i * 32;
                const float4* ej = emb4 + (size_t)j * 32;
                A0[it] = ei[c * 2]; A1[it] = ei[c * 2 + 1];
                B0[it] = ej[c * 2]; B1[it] = ej[c * 2 + 1];
            }
            #pragma unroll
            for (int it = 0; it < 4; ++it) {
                float d = A0[it].x * B0[it].x + A0[it].y * B0[it].y
                        + A0[it].z * B0[it].z + A0[it].w * B0[it].w
                        + A1[it].x * B1[it].x + A1[it].y * B1[it].y
                        + A1[it].z * B1[it].z + A1[it].w * B1[it].w;
                float n = A0[it].x * s0.x + A0[it].y * s0.y
                        + A0[it].z * s0.z + A0[it].w * s0.w
                        + A1[it].x * s1.x + A1[it].y * s1.y
                        + A1[it].z * s1.z + A1[it].w * s1.w;
                #pragma unroll
                for (int off = 8; off > 0; off >>= 1) {
                    d += __shfl_xor(d, off);
                    n += __shfl_xor(n, off);
                }
                const float cost = -logf(expf(d - n) + 1e-8f);
                if (c == 0) acc += cost;         // grp leaders only
            }
        }
        // fold grp leaders (lanes 0,16,32,48) -> lane 0
        acc += __shfl_xor(acc, 16);
        acc += __shfl_xor(acc, 32);

        __syncthreads();
        if (lane == 0) ls[wid] = acc;
        __syncthreads();
        if (threadIdx.x == 0)
            blockpart[blockIdx.x] = ls[0] + ls[1] + ls[2] + ls[3];
    }

    grid.sync();

    // ---------------- Phase D: block 0 reduces blockpart -> mean -----------
    if (blockIdx.x == 0) {
        float s = blockpart[threadIdx.x];        // 256 values, 256 threads
        #pragma unroll
        for (int off = 32; off > 0; off >>= 1) s += __shfl_xor(s, off);
        if (lane == 0) ls[wid] = s;
        __syncthreads();
        if (threadIdx.x == 0)
            out[0] = (ls[0] + ls[1] + ls[2] + ls[3]) / (float)NPAIRS;
    }
}

extern "C" void kernel_launch(void* const* d_in, const int* in_sizes, int n_in,
                              void* d_out, int out_size, void* d_ws, size_t ws_size,
                              hipStream_t stream) {
    const float4* emb4 = (const float4*)d_in[0];
    const int*    iv   = (const int*)d_in[1];
    const int*    jv   = (const int*)d_in[2];
    float* out = (float*)d_out;

    float* partial   = (float*)d_ws;                 // 256*128
    float* blockpart = partial + BLOCKS * DIM;       // 256

    void* args[] = { (void*)&emb4, (void*)&iv, (void*)&jv,
                     (void*)&partial, (void*)&blockpart, (void*)&out };
    hipLaunchCooperativeKernel((const void*)fused, dim3(BLOCKS), dim3(THREADS),
                               args, 0, stream);
}

// Round 7
// 21.985 us; speedup vs baseline: 3.5443x; 3.5443x over previous
//
#include <hip/hip_runtime.h>
#include <math.h>

#define DIM     128
#define V_ROWS  20000
#define NPAIRS  65536
#define NFLOAT4 (V_ROWS * DIM / 4)   // 640000

constexpr int K1_BLOCKS  = 256;
constexpr int K1_THREADS = 256;
constexpr int K1_STRIDE  = K1_BLOCKS * K1_THREADS;   // 65536 float4
constexpr int K1_TAIL    = NFLOAT4 - 9 * K1_STRIDE;  // 50176

constexpr int K2_BLOCKS  = 512;      // 2048 waves x 32 pairs = 65536
constexpr int K2_THREADS = 256;

// ws layout (floats): partial[256*128], blockpart[512]

// ---------------- K1: per-block column partial sums (plain stores) ---------
__global__ __launch_bounds__(K1_THREADS) void k1_colsum(
        const float4* __restrict__ emb4,
        float* __restrict__ partial) {
    const int tid = blockIdx.x * K1_THREADS + threadIdx.x;
    float4 a = make_float4(0.f, 0.f, 0.f, 0.f);
    #pragma unroll
    for (int k = 0; k < 9; ++k) {
        const float4 v = emb4[tid + k * K1_STRIDE];
        a.x += v.x; a.y += v.y; a.z += v.z; a.w += v.w;
    }
    if (tid < K1_TAIL) {
        const float4 v = emb4[tid + 9 * K1_STRIDE];
        a.x += v.x; a.y += v.y; a.z += v.z; a.w += v.w;
    }
    // stride*4 % 128 == 0 -> thread's 4 cols fixed: (tid*4)&127.
    // lane l and l^32 share columns -> fold wave to 32 lanes.
    a.x += __shfl_xor(a.x, 32);
    a.y += __shfl_xor(a.y, 32);
    a.z += __shfl_xor(a.z, 32);
    a.w += __shfl_xor(a.w, 32);

    __shared__ float sm[4][DIM];
    const int wid  = threadIdx.x >> 6;
    const int lane = threadIdx.x & 63;
    const int col  = (threadIdx.x * 4) & 127;
    if (lane < 32) {
        sm[wid][col + 0] = a.x;
        sm[wid][col + 1] = a.y;
        sm[wid][col + 2] = a.z;
        sm[wid][col + 3] = a.w;
    }
    __syncthreads();
    if (threadIdx.x < DIM) {
        partial[blockIdx.x * DIM + threadIdx.x] =
            sm[0][threadIdx.x] + sm[1][threadIdx.x] +
            sm[2][threadIdx.x] + sm[3][threadIdx.x];
    }
}

// ------- K2: per-block fold partial->S_lds, then pairs (32/wave) -----------
__global__ __launch_bounds__(K2_THREADS) void k2_pairs(
        const float4* __restrict__ emb4,   // rows as 32 x float4
        const int* __restrict__ iv,
        const int* __restrict__ jv,
        const float* __restrict__ partial,
        float* __restrict__ blockpart) {
    const int lane = threadIdx.x & 63;
    const int wid  = threadIdx.x >> 6;

    __shared__ float sm[2][DIM];
    __shared__ float S_lds[DIM];
    __shared__ float ls[4];

    // ---- fold 256 partial rows -> S_lds (4 indep accumulators for ILP) ----
    {
        const int col = threadIdx.x & 127;
        const int g   = threadIdx.x >> 7;          // 0..1 -> rows g, g+2, ...
        float s0 = 0.f, s1 = 0.f, s2 = 0.f, s3 = 0.f;
        #pragma unroll 8
        for (int k = 0; k < 32; ++k) {             // 128 rows per group
            s0 += partial[(g + 8 * k + 0) * DIM + col];
            s1 += partial[(g + 8 * k + 2) * DIM + col];
            s2 += partial[(g + 8 * k + 4) * DIM + col];
            s3 += partial[(g + 8 * k + 6) * DIM + col];
        }
        sm[g][col] = (s0 + s1) + (s2 + s3);
        __syncthreads();
        if (threadIdx.x < DIM)
            S_lds[threadIdx.x] = sm[0][threadIdx.x] + sm[1][threadIdx.x];
        __syncthreads();
    }

    // ---------------- pairs: 16 lanes/pair, 32 pairs/wave ------------------
    const int c    = lane & 15;            // 8 cols per lane
    const int grp  = lane >> 4;            // 4 pairs in flight per batch
    const int gw   = blockIdx.x * 4 + wid; // 0..2047
    const int base = gw * 32;              // wave's 32 consecutive pairs

    const float4* S4 = reinterpret_cast<const float4*>(S_lds);
    const float4 s0 = S4[c * 2], s1 = S4[c * 2 + 1];

    // coalesced index load: lanes 0..31 -> iv, lanes 32..63 -> jv
    const int idxval = (lane < 32) ? iv[base + lane] : jv[base + lane - 32];

    float acc = 0.f;
    #pragma unroll
    for (int ot = 0; ot < 2; ++ot) {
        // issue 16 row-pair gathers (4 batches x 4 pairs) before reducing
        float4 A0[4], A1[4], B0[4], B1[4];
        #pragma unroll
        for (int it = 0; it < 4; ++it) {
            const int q = ot * 16 + it * 4 + grp;
            const int i = __shfl(idxval, q);
            const int j = __shfl(idxval, 32 + q);
            const float4* ei = emb4 + (size_t)i * 32;
            const float4* ej = emb4 + (size_t)j * 32;
            A0[it] = ei[c * 2]; A1[it] = ei[c * 2 + 1];
            B0[it] = ej[c * 2]; B1[it] = ej[c * 2 + 1];
        }
        #pragma unroll
        for (int it = 0; it < 4; ++it) {
            float d = A0[it].x * B0[it].x + A0[it].y * B0[it].y
                    + A0[it].z * B0[it].z + A0[it].w * B0[it].w
                    + A1[it].x * B1[it].x + A1[it].y * B1[it].y
                    + A1[it].z * B1[it].z + A1[it].w * B1[it].w;
            float n = A0[it].x * s0.x + A0[it].y * s0.y
                    + A0[it].z * s0.z + A0[it].w * s0.w
                    + A1[it].x * s1.x + A1[it].y * s1.y
                    + A1[it].z * s1.z + A1[it].w * s1.w;
            #pragma unroll
            for (int off = 8; off > 0; off >>= 1) {
                d += __shfl_xor(d, off);
                n += __shfl_xor(n, off);
            }
            const float cost = -logf(expf(d - n) + 1e-8f);
            if (c == 0) acc += cost;       // grp leaders only
        }
    }
    // fold grp leaders (lanes 0,16,32,48) -> lane 0
    acc += __shfl_xor(acc, 16);
    acc += __shfl_xor(acc, 32);

    if (lane == 0) ls[wid] = acc;
    __syncthreads();
    if (threadIdx.x == 0)
        blockpart[blockIdx.x] = ls[0] + ls[1] + ls[2] + ls[3];
}

// ---------------- K3: final reduce (1 block, one parallel load round) ------
__global__ __launch_bounds__(256) void k3_final(
        const float* __restrict__ blockpart,
        float* __restrict__ out) {
    const int t = threadIdx.x;             // 0..255
    float s = blockpart[t] + blockpart[t + 256];
    #pragma unroll
    for (int off = 32; off > 0; off >>= 1) s += __shfl_xor(s, off);
    __shared__ float ls[4];
    if ((t & 63) == 0) ls[t >> 6] = s;
    __syncthreads();
    if (t == 0)
        out[0] = (ls[0] + ls[1] + ls[2] + ls[3]) / (float)NPAIRS;
}

extern "C" void kernel_launch(void* const* d_in, const int* in_sizes, int n_in,
                              void* d_out, int out_size, void* d_ws, size_t ws_size,
                              hipStream_t stream) {
    const float4* emb4 = (const float4*)d_in[0];
    const int*    iv   = (const int*)d_in[1];
    const int*    jv   = (const int*)d_in[2];
    float* out = (float*)d_out;

    float* partial   = (float*)d_ws;                 // 256*128
    float* blockpart = partial + K1_BLOCKS * DIM;    // 512

    hipLaunchKernelGGL(k1_colsum, dim3(K1_BLOCKS), dim3(K1_THREADS), 0, stream,
                       emb4, partial);
    hipLaunchKernelGGL(k2_pairs, dim3(K2_BLOCKS), dim3(K2_THREADS), 0, stream,
                       emb4, iv, jv, partial, blockpart);
    hipLaunchKernelGGL(k3_final, dim3(1), dim3(256), 0, stream,
                       blockpart, out);
}

// Round 8
// 20.111 us; speedup vs baseline: 3.8744x; 1.0932x over previous
//
#include <hip/hip_runtime.h>
#include <math.h>

#define DIM     128
#define V_ROWS  20000
#define NPAIRS  65536
#define NFLOAT4 (V_ROWS * DIM / 4)   // 640000

constexpr int K1_BLOCKS  = 64;
constexpr int K1_THREADS = 256;
constexpr int K1_STRIDE  = K1_BLOCKS * K1_THREADS;       // 16384 float4
constexpr int K1_FULL    = NFLOAT4 / K1_STRIDE;          // 39 full rounds
constexpr int K1_TAIL    = NFLOAT4 - K1_FULL * K1_STRIDE; // 1024

constexpr int K2_BLOCKS  = 512;      // 2048 waves x 32 pairs = 65536
constexpr int K2_THREADS = 256;

// ws layout (floats): partial[64*128], blockpart[512]

// ---------------- K1: per-block column partial sums (plain stores) ---------
__global__ __launch_bounds__(K1_THREADS) void k1_colsum(
        const float4* __restrict__ emb4,
        float* __restrict__ partial) {
    const int tid = blockIdx.x * K1_THREADS + threadIdx.x;
    float4 a0 = make_float4(0.f, 0.f, 0.f, 0.f);
    float4 a1 = a0, a2 = a0, a3 = a0;
    #pragma unroll
    for (int k = 0; k + 3 < K1_FULL; k += 4) {   // 36 loads, 4 indep chains
        const float4 v0 = emb4[tid + (k + 0) * K1_STRIDE];
        const float4 v1 = emb4[tid + (k + 1) * K1_STRIDE];
        const float4 v2 = emb4[tid + (k + 2) * K1_STRIDE];
        const float4 v3 = emb4[tid + (k + 3) * K1_STRIDE];
        a0.x += v0.x; a0.y += v0.y; a0.z += v0.z; a0.w += v0.w;
        a1.x += v1.x; a1.y += v1.y; a1.z += v1.z; a1.w += v1.w;
        a2.x += v2.x; a2.y += v2.y; a2.z += v2.z; a2.w += v2.w;
        a3.x += v3.x; a3.y += v3.y; a3.z += v3.z; a3.w += v3.w;
    }
    {   // rounds 36,37,38 + tail
        const float4 v0 = emb4[tid + 36 * K1_STRIDE];
        const float4 v1 = emb4[tid + 37 * K1_STRIDE];
        const float4 v2 = emb4[tid + 38 * K1_STRIDE];
        a0.x += v0.x; a0.y += v0.y; a0.z += v0.z; a0.w += v0.w;
        a1.x += v1.x; a1.y += v1.y; a1.z += v1.z; a1.w += v1.w;
        a2.x += v2.x; a2.y += v2.y; a2.z += v2.z; a2.w += v2.w;
        if (tid < K1_TAIL) {
            const float4 v3 = emb4[tid + K1_FULL * K1_STRIDE];
            a3.x += v3.x; a3.y += v3.y; a3.z += v3.z; a3.w += v3.w;
        }
    }
    float4 a = make_float4((a0.x + a1.x) + (a2.x + a3.x),
                           (a0.y + a1.y) + (a2.y + a3.y),
                           (a0.z + a1.z) + (a2.z + a3.z),
                           (a0.w + a1.w) + (a2.w + a3.w));
    // stride*4 % 128 == 0 -> thread's 4 cols fixed: (tid*4)&127.
    // lane l and l^32 share columns -> fold wave to 32 lanes.
    a.x += __shfl_xor(a.x, 32);
    a.y += __shfl_xor(a.y, 32);
    a.z += __shfl_xor(a.z, 32);
    a.w += __shfl_xor(a.w, 32);

    __shared__ float sm[4][DIM];
    const int wid  = threadIdx.x >> 6;
    const int lane = threadIdx.x & 63;
    const int col  = (threadIdx.x * 4) & 127;
    if (lane < 32) {
        sm[wid][col + 0] = a.x;
        sm[wid][col + 1] = a.y;
        sm[wid][col + 2] = a.z;
        sm[wid][col + 3] = a.w;
    }
    __syncthreads();
    if (threadIdx.x < DIM) {
        partial[blockIdx.x * DIM + threadIdx.x] =
            sm[0][threadIdx.x] + sm[1][threadIdx.x] +
            sm[2][threadIdx.x] + sm[3][threadIdx.x];
    }
}

// ------- K2: cheap fold partial->S_lds (8 f4 loads/thr), then pairs --------
__global__ __launch_bounds__(K2_THREADS) void k2_pairs(
        const float4* __restrict__ emb4,   // rows as 32 x float4
        const int* __restrict__ iv,
        const int* __restrict__ jv,
        const float4* __restrict__ partial4,  // [64][32] float4
        float* __restrict__ blockpart) {
    const int lane = threadIdx.x & 63;
    const int wid  = threadIdx.x >> 6;

    __shared__ float4 sm4[8][32];
    __shared__ float  S_lds[DIM];
    __shared__ float  ls[4];

    // ---- fold 64 partial rows -> S_lds: 8 independent f4 loads/thread ----
    {
        const int f4c = threadIdx.x & 31;     // float4 column 0..31
        const int g   = threadIdx.x >> 5;     // row group 0..7
        float4 s = make_float4(0.f, 0.f, 0.f, 0.f);
        #pragma unroll
        for (int k = 0; k < 8; ++k) {         // rows g, g+8, ..., g+56
            const float4 v = partial4[(g + 8 * k) * 32 + f4c];
            s.x += v.x; s.y += v.y; s.z += v.z; s.w += v.w;
        }
        sm4[g][f4c] = s;
        __syncthreads();
        if (threadIdx.x < DIM) {
            const float* smf = reinterpret_cast<const float*>(sm4); // [8][128]
            float tot = 0.f;
            #pragma unroll
            for (int g2 = 0; g2 < 8; ++g2) tot += smf[g2 * DIM + threadIdx.x];
            S_lds[threadIdx.x] = tot;
        }
        __syncthreads();
    }

    // ---------------- pairs: 16 lanes/pair, 32 pairs/wave ------------------
    const int c    = lane & 15;            // 8 cols per lane
    const int grp  = lane >> 4;            // 4 pairs in flight per batch
    const int gw   = blockIdx.x * 4 + wid; // 0..2047
    const int base = gw * 32;              // wave's 32 consecutive pairs

    const float4* S4 = reinterpret_cast<const float4*>(S_lds);
    const float4 s0 = S4[c * 2], s1 = S4[c * 2 + 1];

    // coalesced index load: lanes 0..31 -> iv, lanes 32..63 -> jv
    const int idxval = (lane < 32) ? iv[base + lane] : jv[base + lane - 32];

    float acc = 0.f;
    #pragma unroll
    for (int ot = 0; ot < 2; ++ot) {
        // issue 16 row-pair gathers (4 batches x 4 pairs) before reducing
        float4 A0[4], A1[4], B0[4], B1[4];
        #pragma unroll
        for (int it = 0; it < 4; ++it) {
            const int q = ot * 16 + it * 4 + grp;
            const int i = __shfl(idxval, q);
            const int j = __shfl(idxval, 32 + q);
            const float4* ei = emb4 + (size_t)i * 32;
            const float4* ej = emb4 + (size_t)j * 32;
            A0[it] = ei[c * 2]; A1[it] = ei[c * 2 + 1];
            B0[it] = ej[c * 2]; B1[it] = ej[c * 2 + 1];
        }
        #pragma unroll
        for (int it = 0; it < 4; ++it) {
            float d = A0[it].x * B0[it].x + A0[it].y * B0[it].y
                    + A0[it].z * B0[it].z + A0[it].w * B0[it].w
                    + A1[it].x * B1[it].x + A1[it].y * B1[it].y
                    + A1[it].z * B1[it].z + A1[it].w * B1[it].w;
            float n = A0[it].x * s0.x + A0[it].y * s0.y
                    + A0[it].z * s0.z + A0[it].w * s0.w
                    + A1[it].x * s1.x + A1[it].y * s1.y
                    + A1[it].z * s1.z + A1[it].w * s1.w;
            #pragma unroll
            for (int off = 8; off > 0; off >>= 1) {
                d += __shfl_xor(d, off);
                n += __shfl_xor(n, off);
            }
            const float cost = -logf(expf(d - n) + 1e-8f);
            if (c == 0) acc += cost;       // grp leaders only
        }
    }
    // fold grp leaders (lanes 0,16,32,48) -> lane 0
    acc += __shfl_xor(acc, 16);
    acc += __shfl_xor(acc, 32);

    if (lane == 0) ls[wid] = acc;
    __syncthreads();
    if (threadIdx.x == 0)
        blockpart[blockIdx.x] = ls[0] + ls[1] + ls[2] + ls[3];
}

// ---------------- K3: final reduce (1 block, one parallel load round) ------
__global__ __launch_bounds__(256) void k3_final(
        const float* __restrict__ blockpart,
        float* __restrict__ out) {
    const int t = threadIdx.x;             // 0..255
    float s = blockpart[t] + blockpart[t + 256];
    #pragma unroll
    for (int off = 32; off > 0; off >>= 1) s += __shfl_xor(s, off);
    __shared__ float ls[4];
    if ((t & 63) == 0) ls[t >> 6] = s;
    __syncthreads();
    if (t == 0)
        out[0] = (ls[0] + ls[1] + ls[2] + ls[3]) / (float)NPAIRS;
}

extern "C" void kernel_launch(void* const* d_in, const int* in_sizes, int n_in,
                              void* d_out, int out_size, void* d_ws, size_t ws_size,
                              hipStream_t stream) {
    const float4* emb4 = (const float4*)d_in[0];
    const int*    iv   = (const int*)d_in[1];
    const int*    jv   = (const int*)d_in[2];
    float* out = (float*)d_out;

    float* partial   = (float*)d_ws;                 // 64*128
    float* blockpart = partial + K1_BLOCKS * DIM;    // 512

    hipLaunchKernelGGL(k1_colsum, dim3(K1_BLOCKS), dim3(K1_THREADS), 0, stream,
                       emb4, partial);
    hipLaunchKernelGGL(k2_pairs, dim3(K2_BLOCKS), dim3(K2_THREADS), 0, stream,
                       emb4, iv, jv, (const float4*)partial, blockpart);
    hipLaunchKernelGGL(k3_final, dim3(1), dim3(256), 0, stream,
                       blockpart, out);
}